// Round 2
// baseline (549.445 us; speedup 1.0000x reference)
//
#include <hip/hip_runtime.h>
#include <math.h>

namespace {
constexpr int B = 8, T = 4096, D = 1024, H = 8, BW = 128;
constexpr int C = 64;          // T-chunks for the scan
constexpr int L = T / C;       // 64 rows per chunk
constexpr size_t BCD = (size_t)B * C * D;   // 524288
constexpr size_t BTD = (size_t)B * T * D;   // 33554432

__device__ __forceinline__ float fast_exp(float x) { return __expf(x); }
__device__ __forceinline__ float fast_rcp(float x) { return __builtin_amdgcn_rcpf(x); }
__device__ __forceinline__ float fast_sigmoid(float z) {
    return fast_rcp(1.f + __expf(-z));
}
}

// ---- K1: gates + log_a + normed_x + per-chunk log_a sums ------------------
// grid = B*H*C, block = 256. LDS: x tile 32KB + lsum. Weights streamed from
// global (1MB total working set -> L2-resident; per-wave w read = contiguous
// 512B line, L1-friendly). 8 rows x 4 cols x 2 gates per thread.
__global__ __launch_bounds__(256) void k1_gates(
    const float* __restrict__ x, const float* __restrict__ a_param,
    const float* __restrict__ ig_w, const float* __restrict__ ig_b,
    const float* __restrict__ ag_w, const float* __restrict__ ag_b,
    float* __restrict__ log_a, float* __restrict__ nx_out,
    float* __restrict__ logSum)
{
    __shared__ float xs[64][BW];    // 32 KB
    __shared__ float lsum[BW];

    const int bid = blockIdx.x;
    const int c   = bid % C;
    const int h   = (bid / C) % H;
    const int b   = bid / (C * H);
    const int tid = threadIdx.x;
    const int cg  = tid & 31;       // 32 col-groups of 4 cols
    const int rg  = tid >> 5;       // 8 row-groups of 8 rows
    const int j0  = cg * 4;
    const int r0  = rg * 8;
    const int t0  = c * L;

    // stage x tile [64][128] (coalesced float4; read exactly once per block)
    for (int u = tid; u < 64 * 32; u += 256) {
        const int row = u >> 5;
        const int c4  = (u & 31) * 4;
        *(float4*)&xs[row][c4] =
            *(const float4*)&x[((size_t)(b * T + t0 + row)) * D + h * BW + c4];
    }
    if (tid < BW) lsum[tid] = 0.f;
    __syncthreads();

    float sp[4], bi4[4], ba4[4];
    #pragma unroll
    for (int k = 0; k < 4; ++k) {
        sp[k]  = log1pf(__expf(a_param[h * BW + j0 + k]));  // softplus(a_param)
        bi4[k] = ig_b[h * BW + j0 + k];
        ba4[k] = ag_b[h * BW + j0 + k];
    }

    const float* wg = ig_w + (size_t)h * BW * BW + j0;
    const float* wa = ag_w + (size_t)h * BW * BW + j0;

    float ai[8][4] = {{0.f}}, aa[8][4] = {{0.f}};
    for (int i0 = 0; i0 < BW; i0 += 4) {
        float xq[8][4];
        #pragma unroll
        for (int r = 0; r < 8; ++r)                 // LDS: 2 addrs/wave, broadcast
            *(float4*)xq[r] = *(const float4*)&xs[r0 + r][i0];
        #pragma unroll
        for (int di = 0; di < 4; ++di) {
            float wik[4], wak[4];
            *(float4*)wik = *(const float4*)&wg[(size_t)(i0 + di) * BW];
            *(float4*)wak = *(const float4*)&wa[(size_t)(i0 + di) * BW];
            #pragma unroll
            for (int r = 0; r < 8; ++r) {
                const float xv = xq[r][di];
                #pragma unroll
                for (int k = 0; k < 4; ++k) {
                    ai[r][k] = fmaf(xv, wik[k], ai[r][k]);
                    aa[r][k] = fmaf(xv, wak[k], aa[r][k]);
                }
            }
        }
    }

    float csum[4] = {0.f, 0.f, 0.f, 0.f};
    #pragma unroll
    for (int r = 0; r < 8; ++r) {
        const int t = t0 + r0 + r;
        float la4[4], nx4[4];
        #pragma unroll
        for (int k = 0; k < 4; ++k) {
            const float gx = fast_sigmoid(ai[r][k] + bi4[k]);
            const float ga = fast_sigmoid(aa[r][k] + ba4[k]);
            const float la = -8.f * ga * sp[k];
            const float a2 = __expf(2.f * la);
            const float mu = sqrtf(fmaxf(1.f - a2, 1e-7f));
            la4[k] = la;
            nx4[k] = xs[r0 + r][j0 + k] * gx * mu;
            csum[k] += la;
        }
        const size_t gi = ((size_t)(b * T + t)) * D + h * BW + j0;
        *(float4*)&log_a[gi]  = *(const float4*)la4;
        *(float4*)&nx_out[gi] = *(const float4*)nx4;
    }

    #pragma unroll
    for (int k = 0; k < 4; ++k) atomicAdd(&lsum[j0 + k], csum[k]);
    __syncthreads();
    if (tid < BW)
        logSum[((size_t)(b * C + c)) * D + h * BW + tid] = lsum[tid];
}

// ---- tiny inter-chunk exclusive scan (log-sums and z-sums) ----------------
__global__ void k_scan(const float* __restrict__ s, float* __restrict__ o)
{
    const int g = blockIdx.x * blockDim.x + threadIdx.x;  // 0..B*D-1
    const int b = g >> 10, d = g & 1023;
    float off = 0.f;
    for (int c = 0; c < C; ++c) {
        const size_t idx = ((size_t)(b * C + c)) * D + d;
        o[idx] = off;
        off += s[idx];
    }
}

// ---- K3: per-chunk sums of z = nx / q,  q = max(exp(prefix log_a), 1e-7) --
__global__ __launch_bounds__(256) void k3_zsum(
    const float* __restrict__ log_a, const float* __restrict__ nx,
    const float* __restrict__ logOff, float* __restrict__ Zsum)
{
    const int c = blockIdx.x % C, b = blockIdx.x / C;
    const int d = threadIdx.x * 4;
    const size_t cb = ((size_t)(b * C + c)) * D + d;
    float lp[4], zs[4] = {0.f, 0.f, 0.f, 0.f};
    *(float4*)lp = *(const float4*)&logOff[cb];
    size_t base = ((size_t)(b * T + c * L)) * D + d;
    #pragma unroll 4
    for (int t = 0; t < L; ++t, base += D) {
        float la4[4], nv4[4];
        *(float4*)la4 = *(const float4*)&log_a[base];
        *(float4*)nv4 = *(const float4*)&nx[base];
        #pragma unroll
        for (int k = 0; k < 4; ++k) {
            const float qq = fmaxf(__expf(lp[k]), 1e-7f);  // exclusive p_prefix
            zs[k] += nv4[k] * fast_rcp(qq);
            lp[k] += la4[k];
        }
    }
    *(float4*)&Zsum[cb] = *(const float4*)zs;
}

// ---- K5: h = q * (Zoff + local cumsum z); in-place over nx; last_h --------
__global__ __launch_bounds__(256) void k5_final(
    const float* __restrict__ log_a, const float* __restrict__ logOff,
    const float* __restrict__ Zoff, float* y /* in: nx, out: h */,
    float* __restrict__ last_h)
{
    const int c = blockIdx.x % C, b = blockIdx.x / C;
    const int d = threadIdx.x * 4;
    const size_t cb = ((size_t)(b * C + c)) * D + d;
    float lp[4], S[4], h4[4] = {0.f, 0.f, 0.f, 0.f};
    *(float4*)lp = *(const float4*)&logOff[cb];
    *(float4*)S  = *(const float4*)&Zoff[cb];
    size_t base = ((size_t)(b * T + c * L)) * D + d;
    #pragma unroll 4
    for (int t = 0; t < L; ++t, base += D) {
        float la4[4], nv4[4];
        *(float4*)la4 = *(const float4*)&log_a[base];
        *(float4*)nv4 = *(const float4*)&y[base];       // nx (read before write)
        #pragma unroll
        for (int k = 0; k < 4; ++k) {
            const float qq = fmaxf(__expf(lp[k]), 1e-7f);
            S[k] += nv4[k] * fast_rcp(qq);
            h4[k] = qq * S[k];
            lp[k] += la4[k];
        }
        *(float4*)&y[base] = *(const float4*)h4;
    }
    if (c == C - 1)
        *(float4*)&last_h[(size_t)b * D + d] = *(const float4*)h4;
}

extern "C" void kernel_launch(void* const* d_in, const int* in_sizes, int n_in,
                              void* d_out, int out_size, void* d_ws, size_t ws_size,
                              hipStream_t stream)
{
    const float* x       = (const float*)d_in[0];
    // d_in[1] = segment_pos (unused by the reference math)
    const float* a_param = (const float*)d_in[2];
    const float* ig_w    = (const float*)d_in[3];
    const float* ig_b    = (const float*)d_in[4];
    const float* ag_w    = (const float*)d_in[5];
    const float* ag_b    = (const float*)d_in[6];

    float* out    = (float*)d_out;
    float* y      = out;          // [B,T,D]; doubles as nx scratch before K5
    float* last_h = out + BTD;    // [B,D]

    float* w      = (float*)d_ws; // needs 4*BCD + BTD floats = 142.6 MB
    float* logSum = w;
    float* logOff = w + BCD;
    float* Zsum   = w + 2 * BCD;
    float* Zoff   = w + 3 * BCD;
    float* la     = w + 4 * BCD;  // [B,T,D]

    k1_gates<<<B * H * C, 256, 0, stream>>>(x, a_param, ig_w, ig_b, ag_w, ag_b,
                                            la, y, logSum);
    k_scan  <<<(B * D) / 256, 256, 0, stream>>>(logSum, logOff);
    k3_zsum <<<B * C, 256, 0, stream>>>(la, y, logOff, Zsum);
    k_scan  <<<(B * D) / 256, 256, 0, stream>>>(Zsum, Zoff);
    k5_final<<<B * C, 256, 0, stream>>>(la, logOff, Zoff, y, last_h);
}

// Round 4
// 431.754 us; speedup vs baseline: 1.2726x; 1.2726x over previous
//
#include <hip/hip_runtime.h>
#include <math.h>

namespace {
constexpr int B = 8, T = 4096, D = 1024, H = 8, BW = 128;
constexpr int C = 128;         // T-chunks; K1 tile rows == L
constexpr int L = T / C;       // 32 rows per chunk
constexpr size_t BCD = (size_t)B * C * D;   // 1048576
constexpr size_t BTD = (size_t)B * T * D;   // 33554432
constexpr int WFRAG_N = H * 2 * 2 * 4 * 8 * 64 * 8;  // 524288 ushorts = 1MB

typedef __attribute__((ext_vector_type(8))) short short8v;   // 8 x bf16
typedef __attribute__((ext_vector_type(4))) float float4v;   // MFMA acc

__device__ __forceinline__ float fast_rcp(float x) { return __builtin_amdgcn_rcpf(x); }
__device__ __forceinline__ float fast_sigmoid(float z) {
    return fast_rcp(1.f + __expf(-z));
}
__device__ __forceinline__ unsigned short bf16_trunc(float x) {
    return (unsigned short)(__float_as_uint(x) >> 16);
}
__device__ __forceinline__ float bf16_tof(unsigned short u) {
    return __uint_as_float((unsigned)u << 16);
}
}

// ---- K0: split weights into hi/lo bf16, laid out in MFMA B-fragment order.
// idx bits: e(3) | lane(6) | nt(3) | kt(2) | s(1) | g(1) | h(3)  -> 2^19 total.
// Fragment value: w_g[h][ k = kt*32 + (lane>>4)*8 + e ][ n = nt*16 + (lane&15) ]
__global__ void k0_wsplit(const float* __restrict__ ig_w,
                          const float* __restrict__ ag_w,
                          unsigned short* __restrict__ wfrag)
{
    const int idx  = blockIdx.x * 256 + threadIdx.x;
    const int e    = idx & 7;
    const int lane = (idx >> 3) & 63;
    const int nt   = (idx >> 9) & 7;
    const int kt   = (idx >> 12) & 3;
    const int s    = (idx >> 14) & 1;
    const int g    = (idx >> 15) & 1;
    const int h    = (idx >> 16) & 7;
    const int k = kt * 32 + (lane >> 4) * 8 + e;
    const int n = nt * 16 + (lane & 15);
    const float w = (g ? ag_w : ig_w)[(size_t)h * BW * BW + (size_t)k * BW + n];
    const unsigned short hi = bf16_trunc(w);
    wfrag[idx] = s ? bf16_trunc(w - bf16_tof(hi)) : hi;
}

// ---- K1: split-bf16 MFMA gates + log_a + normed_x + per-chunk log_a sums --
// grid = B*C*H (h fastest -> XCD-pinned weight set). 4 waves; wave owns cols
// [wid*32, wid*32+32), all 32 rows. 3-pass split: hi*hi + hi*lo + lo*hi.
__global__ __launch_bounds__(256) void k1_gates(
    const float* __restrict__ x, const float* __restrict__ a_param,
    const float* __restrict__ ig_b, const float* __restrict__ ag_b,
    const unsigned short* __restrict__ wfrag,
    float* __restrict__ log_a, float* __restrict__ nx_out,
    float* __restrict__ logSum)
{
    __shared__ unsigned short xsh[L * BW];   // hi bf16, 8 KB, XOR-swizzled
    __shared__ unsigned short xsl[L * BW];   // lo bf16, 8 KB

    const int bid = blockIdx.x;
    const int h   = bid & 7;
    const int c   = (bid >> 3) & (C - 1);
    const int b   = bid >> 10;
    const int tid  = threadIdx.x;
    const int wid  = tid >> 6;
    const int lane = tid & 63;
    const int t0   = c * L;

    // stage x tile [32][128] -> hi/lo bf16 in LDS (swizzle: byte ^= (row&7)<<4)
    for (int u = tid; u < L * 32; u += 256) {
        const int row = u >> 5;
        const int c4  = (u & 31) * 4;
        const float4 v = *(const float4*)&x[((size_t)(b * T + t0 + row)) * D + h * BW + c4];
        const float vv[4] = {v.x, v.y, v.z, v.w};
        short4 hv, lv;
        {
            unsigned short h0 = bf16_trunc(vv[0]), h1 = bf16_trunc(vv[1]);
            unsigned short h2 = bf16_trunc(vv[2]), h3 = bf16_trunc(vv[3]);
            hv.x = (short)h0; hv.y = (short)h1; hv.z = (short)h2; hv.w = (short)h3;
            lv.x = (short)bf16_trunc(vv[0] - bf16_tof(h0));
            lv.y = (short)bf16_trunc(vv[1] - bf16_tof(h1));
            lv.z = (short)bf16_trunc(vv[2] - bf16_tof(h2));
            lv.w = (short)bf16_trunc(vv[3] - bf16_tof(h3));
        }
        unsigned byte = (unsigned)(row * 256 + c4 * 2);
        byte ^= (unsigned)((row & 7) << 4);
        *(short4*)((char*)xsh + byte) = hv;
        *(short4*)((char*)xsl + byte) = lv;
    }
    __syncthreads();

    const float4v zero4 = {0.f, 0.f, 0.f, 0.f};
    float4v acc[2][2][2];                       // [gate][mt][ntl]
    #pragma unroll
    for (int g = 0; g < 2; ++g)
        #pragma unroll
        for (int mt = 0; mt < 2; ++mt)
            #pragma unroll
            for (int ntl = 0; ntl < 2; ++ntl) acc[g][mt][ntl] = zero4;

    #pragma unroll
    for (int kt = 0; kt < 4; ++kt) {
        short8v a[2][2];                        // [mt][split]
        #pragma unroll
        for (int mt = 0; mt < 2; ++mt) {
            const int r = mt * 16 + (lane & 15);
            unsigned byte = (unsigned)(r * 256 + kt * 64 + (lane >> 4) * 16);
            byte ^= (unsigned)((r & 7) << 4);
            a[mt][0] = *(const short8v*)((const char*)xsh + byte);
            a[mt][1] = *(const short8v*)((const char*)xsl + byte);
        }
        short8v bb[2][2][2];                    // [gate][ntl][split]
        #pragma unroll
        for (int g = 0; g < 2; ++g)
            #pragma unroll
            for (int ntl = 0; ntl < 2; ++ntl)
                #pragma unroll
                for (int s = 0; s < 2; ++s) {
                    const int ntg = wid * 2 + ntl;
                    const size_t fi =
                        ((((((size_t)h * 2 + g) * 2 + s) * 4 + kt) * 8 + ntg) * 64 + lane) * 8;
                    bb[g][ntl][s] = *(const short8v*)&wfrag[fi];
                }
        #pragma unroll
        for (int g = 0; g < 2; ++g)
            #pragma unroll
            for (int mt = 0; mt < 2; ++mt)
                #pragma unroll
                for (int ntl = 0; ntl < 2; ++ntl) {
                    acc[g][mt][ntl] = __builtin_amdgcn_mfma_f32_16x16x32_bf16(
                        a[mt][0], bb[g][ntl][0], acc[g][mt][ntl], 0, 0, 0);
                    acc[g][mt][ntl] = __builtin_amdgcn_mfma_f32_16x16x32_bf16(
                        a[mt][0], bb[g][ntl][1], acc[g][mt][ntl], 0, 0, 0);
                    acc[g][mt][ntl] = __builtin_amdgcn_mfma_f32_16x16x32_bf16(
                        a[mt][1], bb[g][ntl][0], acc[g][mt][ntl], 0, 0, 0);
                }
    }

    // epilogue: C/D layout col = lane&15, row = (lane>>4)*4 + reg  [m89]
    float sp2[2], bi2[2], ba2[2], csum[2] = {0.f, 0.f};
    #pragma unroll
    for (int ntl = 0; ntl < 2; ++ntl) {
        const int col = wid * 32 + ntl * 16 + (lane & 15);
        sp2[ntl] = log1pf(__expf(a_param[h * BW + col]));   // softplus
        bi2[ntl] = ig_b[h * BW + col];
        ba2[ntl] = ag_b[h * BW + col];
    }
    #pragma unroll
    for (int mt = 0; mt < 2; ++mt)
        #pragma unroll
        for (int ntl = 0; ntl < 2; ++ntl) {
            const int col = wid * 32 + ntl * 16 + (lane & 15);
            #pragma unroll
            for (int e = 0; e < 4; ++e) {
                const int tl = mt * 16 + ((lane >> 4) & 3) * 4 + e;
                const float gx = fast_sigmoid(acc[0][mt][ntl][e] + bi2[ntl]);
                const float ga = fast_sigmoid(acc[1][mt][ntl][e] + ba2[ntl]);
                const float la = -8.f * ga * sp2[ntl];
                const float a2 = __expf(2.f * la);
                const float mu = sqrtf(fmaxf(1.f - a2, 1e-7f));
                unsigned byte = (unsigned)(tl * 256 + col * 2);
                byte ^= (unsigned)((tl & 7) << 4);
                const float xv =
                    bf16_tof(*(const unsigned short*)((const char*)xsh + byte)) +
                    bf16_tof(*(const unsigned short*)((const char*)xsl + byte));
                const size_t gi = ((size_t)(b * T + t0 + tl)) * D + h * BW + col;
                log_a[gi]  = la;
                nx_out[gi] = xv * gx * mu;
                csum[ntl] += la;
            }
        }
    // chunk log_a column sums: lanes {l, l^16, l^32, l^48} hold same column
    #pragma unroll
    for (int ntl = 0; ntl < 2; ++ntl) {
        float v = csum[ntl];
        v += __shfl_xor(v, 16);
        v += __shfl_xor(v, 32);
        if ((lane & 48) == 0) {
            const int col = wid * 32 + ntl * 16 + lane;
            logSum[((size_t)(b * C + c)) * D + h * BW + col] = v;
        }
    }
}

// ---- tiny inter-chunk exclusive scan, IN-PLACE, batched loads -------------
__global__ void k_scan(float* __restrict__ s)
{
    const int g = blockIdx.x * blockDim.x + threadIdx.x;  // 0..B*D-1
    const int b = g >> 10, d = g & 1023;
    const size_t base = (size_t)b * C * D + d;
    float off = 0.f;
    for (int c0 = 0; c0 < C; c0 += 8) {
        float v[8];
        #pragma unroll
        for (int j = 0; j < 8; ++j) v[j] = s[base + (size_t)(c0 + j) * D];
        #pragma unroll
        for (int j = 0; j < 8; ++j) {
            s[base + (size_t)(c0 + j) * D] = off;
            off += v[j];
        }
    }
}

// ---- K3: per-chunk sums of z = nx / q,  q = max(exp(prefix log_a), 1e-7) --
__global__ __launch_bounds__(256) void k3_zsum(
    const float* __restrict__ log_a, const float* __restrict__ nx,
    const float* __restrict__ logOff, float* __restrict__ Zsum)
{
    const int c = blockIdx.x & (C - 1), b = blockIdx.x >> 7;
    const int d = threadIdx.x * 4;
    const size_t cb = ((size_t)(b * C + c)) * D + d;
    float lp[4], zs[4] = {0.f, 0.f, 0.f, 0.f};
    *(float4*)lp = *(const float4*)&logOff[cb];
    size_t base = ((size_t)(b * T + c * L)) * D + d;
    float la4[4], nv4[4], lan[4], nvn[4];
    *(float4*)lan = *(const float4*)&log_a[base];
    *(float4*)nvn = *(const float4*)&nx[base];
    #pragma unroll 4
    for (int t = 0; t < L; ++t) {
        *(float4*)la4 = *(const float4*)lan;
        *(float4*)nv4 = *(const float4*)nvn;
        if (t + 1 < L) {
            *(float4*)lan = *(const float4*)&log_a[base + D];
            *(float4*)nvn = *(const float4*)&nx[base + D];
        }
        #pragma unroll
        for (int k = 0; k < 4; ++k) {
            const float qq = fmaxf(__expf(lp[k]), 1e-7f);  // exclusive p_prefix
            zs[k] += nv4[k] * fast_rcp(qq);
            lp[k] += la4[k];
        }
        base += D;
    }
    *(float4*)&Zsum[cb] = *(const float4*)zs;
}

// ---- K5: h = q * (Zoff + local cumsum z); in-place over nx; last_h --------
__global__ __launch_bounds__(256) void k5_final(
    const float* __restrict__ log_a, const float* __restrict__ logOff,
    const float* __restrict__ Zoff, float* y /* in: nx, out: h */,
    float* __restrict__ last_h)
{
    const int c = blockIdx.x & (C - 1), b = blockIdx.x >> 7;
    const int d = threadIdx.x * 4;
    const size_t cb = ((size_t)(b * C + c)) * D + d;
    float lp[4], S[4], h4[4] = {0.f, 0.f, 0.f, 0.f};
    *(float4*)lp = *(const float4*)&logOff[cb];
    *(float4*)S  = *(const float4*)&Zoff[cb];
    size_t base = ((size_t)(b * T + c * L)) * D + d;
    float la4[4], nv4[4], lan[4], nvn[4];
    *(float4*)lan = *(const float4*)&log_a[base];
    *(float4*)nvn = *(const float4*)&y[base];
    #pragma unroll 4
    for (int t = 0; t < L; ++t) {
        *(float4*)la4 = *(const float4*)lan;
        *(float4*)nv4 = *(const float4*)nvn;
        if (t + 1 < L) {
            *(float4*)lan = *(const float4*)&log_a[base + D];
            *(float4*)nvn = *(const float4*)&y[base + D];
        }
        #pragma unroll
        for (int k = 0; k < 4; ++k) {
            const float qq = fmaxf(__expf(lp[k]), 1e-7f);
            S[k] += nv4[k] * fast_rcp(qq);
            h4[k] = qq * S[k];
            lp[k] += la4[k];
        }
        *(float4*)&y[base] = *(const float4*)h4;
        base += D;
    }
    if (c == C - 1)
        *(float4*)&last_h[(size_t)b * D + d] = *(const float4*)h4;
}

extern "C" void kernel_launch(void* const* d_in, const int* in_sizes, int n_in,
                              void* d_out, int out_size, void* d_ws, size_t ws_size,
                              hipStream_t stream)
{
    const float* x       = (const float*)d_in[0];
    // d_in[1] = segment_pos (unused by the reference math)
    const float* a_param = (const float*)d_in[2];
    const float* ig_w    = (const float*)d_in[3];
    const float* ig_b    = (const float*)d_in[4];
    const float* ag_w    = (const float*)d_in[5];
    const float* ag_b    = (const float*)d_in[6];

    float* out    = (float*)d_out;
    float* y      = out;          // [B,T,D]; nx scratch until K5 overwrites with h
    float* last_h = out + BTD;    // [B,D]

    float* w    = (float*)d_ws;   // BTD + 2*BCD floats = 142.6 MB (as round 2)
    float* logS = w;              // [B,C,D] chunk log-sums -> (in-place) offsets
    float* Zs   = w + BCD;        // [B,C,D] chunk z-sums   -> (in-place) offsets
    float* la   = w + 2 * BCD;    // [B,T,D]
    // wfrag (1MB) aliases the Zs region: written by K0, read by K1 only,
    // then K3 overwrites the region with z-sums. BCD floats = 4MB >= 1MB. ok.
    unsigned short* wfrag = (unsigned short*)Zs;

    k0_wsplit<<<WFRAG_N / 256, 256, 0, stream>>>(ig_w, ag_w, wfrag);
    k1_gates <<<B * C * H, 256, 0, stream>>>(x, a_param, ig_b, ag_b, wfrag,
                                             la, y, logS);
    k_scan   <<<(B * D) / 256, 256, 0, stream>>>(logS);
    k3_zsum  <<<B * C, 256, 0, stream>>>(la, y, logS, Zs);
    k_scan   <<<(B * D) / 256, 256, 0, stream>>>(Zs);
    k5_final <<<B * C, 256, 0, stream>>>(la, logS, Zs, y, last_h);
}